// Round 9
// baseline (114.476 us; speedup 1.0000x reference)
//
#include <hip/hip_runtime.h>
#include <hip/hip_bf16.h>

// Problem constants (from reference setup_inputs)
#define B_  16
#define S_  1024
#define D_  300
#define K_  64           // hidden_set_size == compressed dim
#define O_  256          // outputs per batch
#define M_  (B_*S_)      // 16384 rows (b,s)

typedef __attribute__((ext_vector_type(8)))  short s8b;    // 8 x bf16 (4 VGPRs)
typedef __attribute__((ext_vector_type(4)))  float f32x4;
typedef __attribute__((ext_vector_type(16))) float f32x16;

#define MFMA16(a,b,c) __builtin_amdgcn_mfma_f32_16x16x32_bf16((a),(b),(c),0,0,0)
#define MFMA32(a,b,c) __builtin_amdgcn_mfma_f32_32x32x16_bf16((a),(b),(c),0,0,0)

__device__ __forceinline__ unsigned short bf16_bits(float f) {
    return __builtin_bit_cast(unsigned short, __float2bfloat16(f));
}

// ---------------------------------------------------------------------------
// Fragment-major layouts (16B chunks, indexed as uint4):
//  XcF chunk[(mtile*4 + ks)*64 + half*32 + l31] = Xc[mtile*32+l31][ks*16+half*8 .. +7]
//      (mtile = global bs row / 32; exactly the B-fragment of mfma_32x32x16)
//  HbF chunk[o*512 + nt*256 + ks*64 + half*32 + l31] = H[o][nt*32+l31][ks*16+half*8 .. +7]
//      (exactly the A-fragment)
// In k_fused every fragment load is ONE dwordx4 over 1024 CONTIGUOUS bytes.
// ---------------------------------------------------------------------------

// ---------------------------------------------------------------------------
// Kernel 1 (k_prep):
//   blocks [0, 512)    : compress GEMM for one 32-row m-tile ->
//                        bf16(Xs @ W^T + b), transposed to frag-major XcF
//                        via a padded LDS bounce (32 x 72 elements).
//   blocks [512, 1024) : H f32 -> frag-major HbF, 8 el/thread, coalesced.
//   block  1024        : out[16*256] = 0 (k_fused accumulates with atomics).
// ---------------------------------------------------------------------------
#define C_BLK 512
#define H_BLK 512     // 256*64*64/8/256
#define LT    72      // LDS transpose row stride (elements; 144 B, 16B-aligned)

__global__ __launch_bounds__(256) void k_prep(
        const float* __restrict__ Xs, const float* __restrict__ W,
        const float* __restrict__ bias, const float* __restrict__ H,
        __hip_bfloat16* __restrict__ XcF, __hip_bfloat16* __restrict__ HbF,
        float* __restrict__ out) {
    __shared__ __hip_bfloat16 lt[32 * LT];     // 4608 B
    int bx = blockIdx.x, tid = threadIdx.x;

    if (bx >= C_BLK) {
        if (bx >= C_BLK + H_BLK) {             // ---- zero out[4096] ----
            float4 z = {0.f,0.f,0.f,0.f};
            float4* o4 = (float4*)out;
#pragma unroll
            for (int i = 0; i < 4; ++i) o4[tid * 4 + i] = z;
            return;
        }
        // ---- H -> HbF (frag-major) ----
        int g8 = (bx - C_BLK) * 256 + tid;     // 8-element group index
        const float* src = H + (size_t)g8 * 8;
        float4 f0 = *(const float4*)(src);
        float4 f1 = *(const float4*)(src + 4);
        union { unsigned short us[8]; uint4 q; } pk;
        pk.us[0]=bf16_bits(f0.x); pk.us[1]=bf16_bits(f0.y);
        pk.us[2]=bf16_bits(f0.z); pk.us[3]=bf16_bits(f0.w);
        pk.us[4]=bf16_bits(f1.x); pk.us[5]=bf16_bits(f1.y);
        pk.us[6]=bf16_bits(f1.z); pk.us[7]=bf16_bits(f1.w);
        int k8 = g8 & 7, n = (g8 >> 3) & 63, o = g8 >> 9;
        int idx = o * 512 + (n >> 5) * 256 + (k8 >> 1) * 64
                + (k8 & 1) * 32 + (n & 31);
        ((uint4*)HbF)[idx] = pk.q;             // 8 full 128B lines per wave-instr
        return;
    }

    // ---- compress: m-tile = 32 bs-rows x 64 out-k; 4 waves of 16x32 ----
    int w    = tid >> 6, lane = tid & 63;
    int q    = lane >> 4, r = lane & 15;
    int lrow0 = (w & 1) * 16;                  // local row base of this wave
    int col0  = (w >> 1) * 32;
    int row0  = bx * 32 + lrow0;               // global bs row base

    f32x4 acc0 = {0.f,0.f,0.f,0.f}, acc1 = {0.f,0.f,0.f,0.f};
    const float* arow  = Xs + (size_t)(row0 + r) * D_;        // A: bs row
    const float* brow0 = W  + (size_t)(col0 + r) * D_;        // B: out-k rows
    const float* brow1 = W  + (size_t)(col0 + 16 + r) * D_;
    const float4 z4 = {0.f,0.f,0.f,0.f};

#pragma unroll
    for (int ks = 0; ks < 10; ++ks) {
        int k0 = ks * 32 + q * 8;
        float4 a0 = (k0     < D_) ? *(const float4*)(arow  + k0)     : z4;
        float4 a1 = (k0 + 4 < D_) ? *(const float4*)(arow  + k0 + 4) : z4;
        float4 b0 = (k0     < D_) ? *(const float4*)(brow0 + k0)     : z4;
        float4 b1 = (k0 + 4 < D_) ? *(const float4*)(brow0 + k0 + 4) : z4;
        float4 c0 = (k0     < D_) ? *(const float4*)(brow1 + k0)     : z4;
        float4 c1 = (k0 + 4 < D_) ? *(const float4*)(brow1 + k0 + 4) : z4;
        union { unsigned short us[8]; s8b v; } pa, pb, pc;
        pa.us[0]=bf16_bits(a0.x); pa.us[1]=bf16_bits(a0.y);
        pa.us[2]=bf16_bits(a0.z); pa.us[3]=bf16_bits(a0.w);
        pa.us[4]=bf16_bits(a1.x); pa.us[5]=bf16_bits(a1.y);
        pa.us[6]=bf16_bits(a1.z); pa.us[7]=bf16_bits(a1.w);
        pb.us[0]=bf16_bits(b0.x); pb.us[1]=bf16_bits(b0.y);
        pb.us[2]=bf16_bits(b0.z); pb.us[3]=bf16_bits(b0.w);
        pb.us[4]=bf16_bits(b1.x); pb.us[5]=bf16_bits(b1.y);
        pb.us[6]=bf16_bits(b1.z); pb.us[7]=bf16_bits(b1.w);
        pc.us[0]=bf16_bits(c0.x); pc.us[1]=bf16_bits(c0.y);
        pc.us[2]=bf16_bits(c0.z); pc.us[3]=bf16_bits(c0.w);
        pc.us[4]=bf16_bits(c1.x); pc.us[5]=bf16_bits(c1.y);
        pc.us[6]=bf16_bits(c1.z); pc.us[7]=bf16_bits(c1.w);
        acc0 = MFMA16(pa.v, pb.v, acc0);       // cols col0+0..15
        acc1 = MFMA16(pa.v, pc.v, acc1);       // cols col0+16..31
    }
    // C/D layout: col = lane&15 (out-k), row = quad*4 + i (bs).  Write the
    // 16x32 tile (+bias, bf16-rounded) into the padded LDS transpose buffer.
#pragma unroll
    for (int i = 0; i < 4; ++i) {
        int lr = lrow0 + q * 4 + i;
        int c0i = col0 + r;
        lt[lr * LT + c0i]      = __float2bfloat16(acc0[i] + bias[c0i]);
        lt[lr * LT + c0i + 16] = __float2bfloat16(acc1[i] + bias[c0i + 16]);
    }
    __syncthreads();
    // Re-read as fragment chunks and store coalesced: thread tid = chunk
    // (ks = tid>>6, half = (tid>>5)&1, l31 = tid&31) -> XcF[bx*256 + tid].
    {
        int l31 = tid & 31, hf = (tid >> 5) & 1, ks = tid >> 6;
        uint4 ch = *(const uint4*)(&lt[l31 * LT + ks * 16 + hf * 8]);
        ((uint4*)XcF)[bx * 256 + tid] = ch;    // fully contiguous per wave
    }
}

// ---------------------------------------------------------------------------
// Kernel 2 (k_fused): bipartite GEMM + relu + max-over-n + sum-over-s.
// NO LDS, NO BARRIERS.  Every fragment load is one dwordx4 over 1024
// contiguous bytes (frag-major layouts).  Each wave owns TWO outputs:
// the same 4 B-frag loads feed 16 MFMAs (4 independent chains of 4),
// halving XcF traffic vs 1-o waves (512 -> 256 MB L2 reads device-wide).
// XCD swizzle: batch = (bx&7)*2 + ((bx>>3)&1), so all blocks reading a given
// 128 KB batch slice sit on ONE XCD (round-robin bx%8 -> XCD) -> per-XCD L2
// working set 256 KB, maximal line reuse.
// 32x32x16 MFMA, A = H (n rows), B = Xc (bs cols):
//   C col = lane&31 = bs, row = (reg&3)+8*(reg>>2)+4*(lane>>5) = n.
// Block = 4 waves covering 8 o's; each wave does 16 m-tiles (half of S).
// Grid: 16 batches x 32 o-octets x 2 s-halves = 1024 blocks.
// ~160 VGPR -> 3 waves/SIMD.
// ---------------------------------------------------------------------------
__global__ __launch_bounds__(256, 3) void k_fused(
        const __hip_bfloat16* __restrict__ XcF,
        const __hip_bfloat16* __restrict__ HbF,
        float* __restrict__ out) {
    int tid   = threadIdx.x;
    int w     = tid >> 6, lane = tid & 63;
    int bx    = blockIdx.x;
    int batch = (bx & 7) * 2 + ((bx >> 3) & 1);   // XCD-local batches
    int og    = (bx >> 4) & 31;   // 0..31 : o-octet
    int sh    = (bx >> 9) & 1;    // 0..1  : which half of S
    int o0    = og * 8 + w * 2;   // this wave: o0 and o0+1

    const uint4* hb = (const uint4*)HbF;
    const uint4* xf = (const uint4*)XcF
                    + (size_t)batch * (32 * 256) + (size_t)sh * (16 * 256);

    // A fragments: 2 o's x 2 n-tiles x 4 k-steps, contiguous 1KB loads.
    s8b af[2][2][4];
#pragma unroll
    for (int oi = 0; oi < 2; ++oi)
#pragma unroll
        for (int nt = 0; nt < 2; ++nt)
#pragma unroll
            for (int ks = 0; ks < 4; ++ks)
                af[oi][nt][ks] = __builtin_bit_cast(s8b,
                    hb[(o0 + oi) * 512 + nt * 256 + ks * 64 + lane]);

    float total0 = 0.0f, total1 = 0.0f;
#pragma unroll 2
    for (int mt = 0; mt < 16; ++mt) {
        // B fragments: 4 contiguous 1KB loads, shared by both o's.
        s8b bf[4];
#pragma unroll
        for (int ks = 0; ks < 4; ++ks)
            bf[ks] = __builtin_bit_cast(s8b, xf[mt * 256 + ks * 64 + lane]);

        f32x16 zz = {0.f,0.f,0.f,0.f,0.f,0.f,0.f,0.f,
                     0.f,0.f,0.f,0.f,0.f,0.f,0.f,0.f};
        f32x16 a00 = zz, a01 = zz, a10 = zz, a11 = zz;
#pragma unroll
        for (int ks = 0; ks < 4; ++ks) {       // 4 independent chains
            a00 = MFMA32(af[0][0][ks], bf[ks], a00);
            a01 = MFMA32(af[0][1][ks], bf[ks], a01);
            a10 = MFMA32(af[1][0][ks], bf[ks], a10);
            a11 = MFMA32(af[1][1][ks], bf[ks], a11);
        }
        // Max over the 32 in-lane n-values per o, balanced trees.
        float p0 = fmaxf(fmaxf(a00[0],  a00[1]),  fmaxf(a00[2],  a00[3]));
        float p1 = fmaxf(fmaxf(a00[4],  a00[5]),  fmaxf(a00[6],  a00[7]));
        float p2 = fmaxf(fmaxf(a00[8],  a00[9]),  fmaxf(a00[10], a00[11]));
        float p3 = fmaxf(fmaxf(a00[12], a00[13]), fmaxf(a00[14], a00[15]));
        float p4 = fmaxf(fmaxf(a01[0],  a01[1]),  fmaxf(a01[2],  a01[3]));
        float p5 = fmaxf(fmaxf(a01[4],  a01[5]),  fmaxf(a01[6],  a01[7]));
        float p6 = fmaxf(fmaxf(a01[8],  a01[9]),  fmaxf(a01[10], a01[11]));
        float p7 = fmaxf(fmaxf(a01[12], a01[13]), fmaxf(a01[14], a01[15]));
        float v0 = fmaxf(fmaxf(fmaxf(p0, p1), fmaxf(p2, p3)),
                         fmaxf(fmaxf(p4, p5), fmaxf(p6, p7)));
        float q0 = fmaxf(fmaxf(a10[0],  a10[1]),  fmaxf(a10[2],  a10[3]));
        float q1 = fmaxf(fmaxf(a10[4],  a10[5]),  fmaxf(a10[6],  a10[7]));
        float q2 = fmaxf(fmaxf(a10[8],  a10[9]),  fmaxf(a10[10], a10[11]));
        float q3 = fmaxf(fmaxf(a10[12], a10[13]), fmaxf(a10[14], a10[15]));
        float q4 = fmaxf(fmaxf(a11[0],  a11[1]),  fmaxf(a11[2],  a11[3]));
        float q5 = fmaxf(fmaxf(a11[4],  a11[5]),  fmaxf(a11[6],  a11[7]));
        float q6 = fmaxf(fmaxf(a11[8],  a11[9]),  fmaxf(a11[10], a11[11]));
        float q7 = fmaxf(fmaxf(a11[12], a11[13]), fmaxf(a11[14], a11[15]));
        float v1 = fmaxf(fmaxf(fmaxf(q0, q1), fmaxf(q2, q3)),
                         fmaxf(fmaxf(q4, q5), fmaxf(q6, q7)));
        // Batched cross-half merges (other half holds n = 32..63).
        float s0 = __shfl_xor(v0, 32);
        float s1 = __shfl_xor(v1, 32);
        total0 += fmaxf(fmaxf(v0, s0), 0.0f);  // relu folded into max
        total1 += fmaxf(fmaxf(v1, s1), 0.0f);
    }
    // Sum the 32 bs columns (both halves hold identical totals); batched.
#pragma unroll
    for (int d = 1; d <= 16; d <<= 1) {
        float s0 = __shfl_xor(total0, d);
        float s1 = __shfl_xor(total1, d);
        total0 += s0;
        total1 += s1;
    }
    if (lane == 0) {
        atomicAdd(out + batch * O_ + o0,     total0);
        atomicAdd(out + batch * O_ + o0 + 1, total1);
    }
}

// ---------------------------------------------------------------------------
extern "C" void kernel_launch(void* const* d_in, const int* in_sizes, int n_in,
                              void* d_out, int out_size, void* d_ws, size_t ws_size,
                              hipStream_t stream) {
    const float* Xs   = (const float*)d_in[0];   // [16,1024,300]
    const float* W    = (const float*)d_in[1];   // [64,300]
    const float* bias = (const float*)d_in[2];   // [64]
    const float* H    = (const float*)d_in[3];   // [256,64,64]
    float* out = (float*)d_out;                  // [16,256] f32

    char* ws = (char*)d_ws;
    __hip_bfloat16* HbF = (__hip_bfloat16*)(ws);              // 2,097,152 B
    __hip_bfloat16* XcF = (__hip_bfloat16*)(ws + 2097152);    // 2,097,152 B

    k_prep <<<C_BLK + H_BLK + 1, 256, 0, stream>>>(Xs, W, bias, H, XcF, HbF, out);
    k_fused<<<1024, 256, 0, stream>>>(XcF, HbF, out);
}

// Round 10
// 110.951 us; speedup vs baseline: 1.0318x; 1.0318x over previous
//
#include <hip/hip_runtime.h>
#include <hip/hip_bf16.h>

// Problem constants (from reference setup_inputs)
#define B_  16
#define S_  1024
#define D_  300
#define K_  64           // hidden_set_size == compressed dim
#define O_  256          // outputs per batch
#define M_  (B_*S_)      // 16384 rows (b,s)

typedef __attribute__((ext_vector_type(8)))  short s8b;    // 8 x bf16 (4 VGPRs)
typedef __attribute__((ext_vector_type(4)))  float f32x4;
typedef __attribute__((ext_vector_type(16))) float f32x16;

#define MFMA16(a,b,c) __builtin_amdgcn_mfma_f32_16x16x32_bf16((a),(b),(c),0,0,0)
#define MFMA32(a,b,c) __builtin_amdgcn_mfma_f32_32x32x16_bf16((a),(b),(c),0,0,0)

__device__ __forceinline__ unsigned short bf16_bits(float f) {
    return __builtin_bit_cast(unsigned short, __float2bfloat16(f));
}
__device__ __forceinline__ float max3f(float a, float b, float c) {
    return fmaxf(fmaxf(a, b), c);              // -> v_max3_f32
}

// ---------------------------------------------------------------------------
// Fragment-major layouts (16B chunks, indexed as uint4):
//  XcF chunk[(mtile*4 + ks)*64 + half*32 + l31] = Xc[mtile*32+l31][ks*16+half*8 .. +7]
//      (exactly the B-fragment of mfma_32x32x16; mtile = global bs row / 32)
//  HbF chunk[o*512 + nt*256 + ks*64 + half*32 + l31] = H[o][nt*32+l31][ks*16+half*8 .. +7]
//      (exactly the A-fragment)
// In k_fused every fragment load is ONE dwordx4 over 1024 CONTIGUOUS bytes.
// ---------------------------------------------------------------------------

// ---------------------------------------------------------------------------
// Kernel 1 (k_prep):
//   blocks [0, 512)    : compress GEMM for one 32-row m-tile ->
//                        bf16(Xs @ W^T + b), transposed to frag-major XcF
//                        via a padded LDS bounce (32 x 72 elements).
//   blocks [512, 1024) : H f32 -> frag-major HbF, 8 el/thread, coalesced.
// ---------------------------------------------------------------------------
#define C_BLK 512
#define H_BLK 512     // 256*64*64/8/256
#define LT    72      // LDS transpose row stride (elements; 144 B, 16B-aligned)

__global__ __launch_bounds__(256) void k_prep(
        const float* __restrict__ Xs, const float* __restrict__ W,
        const float* __restrict__ bias, const float* __restrict__ H,
        __hip_bfloat16* __restrict__ XcF, __hip_bfloat16* __restrict__ HbF) {
    __shared__ __hip_bfloat16 lt[32 * LT];     // 4608 B
    int bx = blockIdx.x, tid = threadIdx.x;

    if (bx >= C_BLK) {                         // ---- H -> HbF (frag-major) ----
        int g8 = (bx - C_BLK) * 256 + tid;     // 8-element group index
        const float* src = H + (size_t)g8 * 8;
        float4 f0 = *(const float4*)(src);
        float4 f1 = *(const float4*)(src + 4);
        union { unsigned short us[8]; uint4 q; } pk;
        pk.us[0]=bf16_bits(f0.x); pk.us[1]=bf16_bits(f0.y);
        pk.us[2]=bf16_bits(f0.z); pk.us[3]=bf16_bits(f0.w);
        pk.us[4]=bf16_bits(f1.x); pk.us[5]=bf16_bits(f1.y);
        pk.us[6]=bf16_bits(f1.z); pk.us[7]=bf16_bits(f1.w);
        int k8 = g8 & 7, n = (g8 >> 3) & 63, o = g8 >> 9;
        int idx = o * 512 + (n >> 5) * 256 + (k8 >> 1) * 64
                + (k8 & 1) * 32 + (n & 31);
        ((uint4*)HbF)[idx] = pk.q;             // 8 full 128B lines per wave-instr
        return;
    }

    // ---- compress: m-tile = 32 bs-rows x 64 out-k; 4 waves of 16x32 ----
    int w    = tid >> 6, lane = tid & 63;
    int q    = lane >> 4, r = lane & 15;
    int lrow0 = (w & 1) * 16;                  // local row base of this wave
    int col0  = (w >> 1) * 32;
    int row0  = bx * 32 + lrow0;               // global bs row base

    f32x4 acc0 = {0.f,0.f,0.f,0.f}, acc1 = {0.f,0.f,0.f,0.f};
    const float* arow  = Xs + (size_t)(row0 + r) * D_;        // A: bs row
    const float* brow0 = W  + (size_t)(col0 + r) * D_;        // B: out-k rows
    const float* brow1 = W  + (size_t)(col0 + 16 + r) * D_;
    const float4 z4 = {0.f,0.f,0.f,0.f};

#pragma unroll
    for (int ks = 0; ks < 10; ++ks) {
        int k0 = ks * 32 + q * 8;
        float4 a0 = (k0     < D_) ? *(const float4*)(arow  + k0)     : z4;
        float4 a1 = (k0 + 4 < D_) ? *(const float4*)(arow  + k0 + 4) : z4;
        float4 b0 = (k0     < D_) ? *(const float4*)(brow0 + k0)     : z4;
        float4 b1 = (k0 + 4 < D_) ? *(const float4*)(brow0 + k0 + 4) : z4;
        float4 c0 = (k0     < D_) ? *(const float4*)(brow1 + k0)     : z4;
        float4 c1 = (k0 + 4 < D_) ? *(const float4*)(brow1 + k0 + 4) : z4;
        union { unsigned short us[8]; s8b v; } pa, pb, pc;
        pa.us[0]=bf16_bits(a0.x); pa.us[1]=bf16_bits(a0.y);
        pa.us[2]=bf16_bits(a0.z); pa.us[3]=bf16_bits(a0.w);
        pa.us[4]=bf16_bits(a1.x); pa.us[5]=bf16_bits(a1.y);
        pa.us[6]=bf16_bits(a1.z); pa.us[7]=bf16_bits(a1.w);
        pb.us[0]=bf16_bits(b0.x); pb.us[1]=bf16_bits(b0.y);
        pb.us[2]=bf16_bits(b0.z); pb.us[3]=bf16_bits(b0.w);
        pb.us[4]=bf16_bits(b1.x); pb.us[5]=bf16_bits(b1.y);
        pb.us[6]=bf16_bits(b1.z); pb.us[7]=bf16_bits(b1.w);
        pc.us[0]=bf16_bits(c0.x); pc.us[1]=bf16_bits(c0.y);
        pc.us[2]=bf16_bits(c0.z); pc.us[3]=bf16_bits(c0.w);
        pc.us[4]=bf16_bits(c1.x); pc.us[5]=bf16_bits(c1.y);
        pc.us[6]=bf16_bits(c1.z); pc.us[7]=bf16_bits(c1.w);
        acc0 = MFMA16(pa.v, pb.v, acc0);       // cols col0+0..15
        acc1 = MFMA16(pa.v, pc.v, acc1);       // cols col0+16..31
    }
    // C/D layout: col = lane&15 (out-k), row = quad*4 + i (bs).  Write the
    // 16x32 tile (+bias, bf16-rounded) into the padded LDS transpose buffer.
#pragma unroll
    for (int i = 0; i < 4; ++i) {
        int lr = lrow0 + q * 4 + i;
        int c0i = col0 + r;
        lt[lr * LT + c0i]      = __float2bfloat16(acc0[i] + bias[c0i]);
        lt[lr * LT + c0i + 16] = __float2bfloat16(acc1[i] + bias[c0i + 16]);
    }
    __syncthreads();
    // Re-read as fragment chunks and store coalesced: thread tid = chunk
    // (ks = tid>>6, half = (tid>>5)&1, l31 = tid&31) -> XcF[bx*256 + tid].
    {
        int l31 = tid & 31, hf = (tid >> 5) & 1, ks = tid >> 6;
        uint4 ch = *(const uint4*)(&lt[l31 * LT + ks * 16 + hf * 8]);
        ((uint4*)XcF)[bx * 256 + tid] = ch;    // fully contiguous per wave
    }
}

// ---------------------------------------------------------------------------
// Kernel 2 (k_fused): bipartite GEMM + relu + max-over-n + sum-over-s.
// THIN WAVES for MFMA-pipe saturation: 1 o per wave, ~120 unified regs ->
// 4 waves/SIMD; grid 1024 = exactly 4 blocks/CU, ALL resident, no tail.
// NO LDS, NO BARRIERS, NO ATOMICS.  Every fragment load is one dwordx4 over
// 1024 contiguous bytes; the block's 4 waves read the SAME XcF slice in
// lockstep -> L1 dedupe.  kZero trick: first MFMA of each chain consumes a
// persistent zero accumulator, eliminating 64 accvgpr zero-inits per mt.
// 32x32x16 MFMA, A = H (n rows), B = Xc (bs cols):
//   C col = lane&31 = bs, row = (reg&3)+8*(reg>>2)+4*(lane>>5) = n.
// XCD swizzle: batch = (bx&7)*2 + ((bx>>3)&1) keeps one batch's readers on
// one XCD's L2.  Grid: 16 batches x 64 o-quads = 1024 blocks.
// ---------------------------------------------------------------------------
__global__ __launch_bounds__(256, 4) void k_fused(
        const __hip_bfloat16* __restrict__ XcF,
        const __hip_bfloat16* __restrict__ HbF,
        float* __restrict__ out) {
    int tid   = threadIdx.x;
    int w     = tid >> 6, lane = tid & 63;
    int bx    = blockIdx.x;
    int batch = (bx & 7) * 2 + ((bx >> 3) & 1);   // XCD-local batches
    int og    = bx >> 4;          // 0..63 : o-quad
    int o     = og * 4 + w;       // this wave's output

    const uint4* hb = (const uint4*)HbF;
    const uint4* xf = (const uint4*)XcF + (size_t)batch * (32 * 256);

    // A fragments: 2 n-tiles x 4 k-steps, each a contiguous 1KB load (32 VGPR).
    s8b af[2][4];
#pragma unroll
    for (int nt = 0; nt < 2; ++nt)
#pragma unroll
        for (int ks = 0; ks < 4; ++ks)
            af[nt][ks] = __builtin_bit_cast(s8b,
                hb[o * 512 + nt * 256 + ks * 64 + lane]);

    const f32x16 kZero = {0.f,0.f,0.f,0.f,0.f,0.f,0.f,0.f,
                          0.f,0.f,0.f,0.f,0.f,0.f,0.f,0.f};

    float total = 0.0f;
    for (int mt = 0; mt < 32; ++mt) {
        // B fragments: 4 contiguous 1KB loads (L1/L2-resident).
        s8b bf[4];
#pragma unroll
        for (int ks = 0; ks < 4; ++ks)
            bf[ks] = __builtin_bit_cast(s8b, xf[mt * 256 + ks * 64 + lane]);

        // Two independent 4-chains; first MFMA consumes kZero (no acc init).
        f32x16 a0 = MFMA32(af[0][0], bf[0], kZero);
        f32x16 a1 = MFMA32(af[1][0], bf[0], kZero);
#pragma unroll
        for (int ks = 1; ks < 4; ++ks) {
            a0 = MFMA32(af[0][ks], bf[ks], a0);
            a1 = MFMA32(af[1][ks], bf[ks], a1);
        }
        // Max over the 32 in-lane n-values, max3-shaped (v_max3_f32).
        float u0 = max3f(a0[0],  a0[1],  a0[2]);
        float u1 = max3f(a0[3],  a0[4],  a0[5]);
        float u2 = max3f(a0[6],  a0[7],  a0[8]);
        float u3 = max3f(a0[9],  a0[10], a0[11]);
        float u4 = max3f(a0[12], a0[13], a0[14]);
        float u5 = max3f(a1[0],  a1[1],  a1[2]);
        float u6 = max3f(a1[3],  a1[4],  a1[5]);
        float u7 = max3f(a1[6],  a1[7],  a1[8]);
        float u8 = max3f(a1[9],  a1[10], a1[11]);
        float u9 = max3f(a1[12], a1[13], a1[14]);
        float t0 = max3f(u0, u1, u2);
        float t1 = max3f(u3, u4, u5);
        float t2 = max3f(u6, u7, u8);
        float t3 = max3f(u9, a0[15], a1[15]);
        float v  = fmaxf(fmaxf(t0, t1), fmaxf(t2, t3));
        v = fmaxf(v, __shfl_xor(v, 32));       // other half's 32 n-rows
        v = fmaxf(v, 0.0f);                    // relu folded into max
        total += v;                            // lane's bs col (replicated)
    }
    // Sum the 32 bs columns (both halves hold identical totals).
    total += __shfl_xor(total, 1);
    total += __shfl_xor(total, 2);
    total += __shfl_xor(total, 4);
    total += __shfl_xor(total, 8);
    total += __shfl_xor(total, 16);
    if (lane == 0) out[batch * O_ + o] = total;   // plain store
}

// ---------------------------------------------------------------------------
extern "C" void kernel_launch(void* const* d_in, const int* in_sizes, int n_in,
                              void* d_out, int out_size, void* d_ws, size_t ws_size,
                              hipStream_t stream) {
    const float* Xs   = (const float*)d_in[0];   // [16,1024,300]
    const float* W    = (const float*)d_in[1];   // [64,300]
    const float* bias = (const float*)d_in[2];   // [64]
    const float* H    = (const float*)d_in[3];   // [256,64,64]
    float* out = (float*)d_out;                  // [16,256] f32

    char* ws = (char*)d_ws;
    __hip_bfloat16* HbF = (__hip_bfloat16*)(ws);              // 2,097,152 B
    __hip_bfloat16* XcF = (__hip_bfloat16*)(ws + 2097152);    // 2,097,152 B

    k_prep <<<C_BLK + H_BLK, 256, 0, stream>>>(Xs, W, bias, H, XcF, HbF);
    k_fused<<<B_ * (O_ / 4), 256, 0, stream>>>(XcF, HbF, out);
}